// Round 1
// baseline (4170.657 us; speedup 1.0000x reference)
//
#include <hip/hip_runtime.h>
#include <cstdint>

// ---------------------------------------------------------------------------
// Threefry-2x32, 20 rounds — exact JAX schedule (jax/_src/prng.py)
// ---------------------------------------------------------------------------
static __host__ __device__ inline void tf2x32(uint32_t k0, uint32_t k1,
                                              uint32_t x0, uint32_t x1,
                                              uint32_t &o0, uint32_t &o1) {
  uint32_t ks2 = k0 ^ k1 ^ 0x1BD11BDAu;
  x0 += k0; x1 += k1;
#define TF_R(r) do { x0 += x1; x1 = (x1 << (r)) | (x1 >> (32 - (r))); x1 ^= x0; } while (0)
  TF_R(13); TF_R(15); TF_R(26); TF_R(6);
  x0 += k1; x1 += ks2 + 1u;
  TF_R(17); TF_R(29); TF_R(16); TF_R(24);
  x0 += ks2; x1 += k0 + 2u;
  TF_R(13); TF_R(15); TF_R(26); TF_R(6);
  x0 += k0; x1 += k1 + 3u;
  TF_R(17); TF_R(29); TF_R(16); TF_R(24);
  x0 += k1; x1 += ks2 + 4u;
  TF_R(13); TF_R(15); TF_R(26); TF_R(6);
  x0 += ks2; x1 += k0 + 5u;
#undef TF_R
  o0 = x0; o1 = x1;
}

// XLA's f32 erf_inv expansion (Giles poly, w = -log1p(-x*x)) — matches the
// reference's lax.erf_inv lowering.
__device__ __forceinline__ float erfinv_xla_f32(float x) {
  float w = -log1pf(-x * x);
  float p;
  if (w < 5.0f) {
    w -= 2.5f;
    p = 2.81022636e-08f;
    p = fmaf(p, w, 3.43273939e-07f);
    p = fmaf(p, w, -3.5233877e-06f);
    p = fmaf(p, w, -4.39150654e-06f);
    p = fmaf(p, w, 0.00021858087f);
    p = fmaf(p, w, -0.00125372503f);
    p = fmaf(p, w, -0.00417768164f);
    p = fmaf(p, w, 0.246640727f);
    p = fmaf(p, w, 1.50140941f);
  } else {
    w = sqrtf(w) - 3.0f;
    p = -0.000200214257f;
    p = fmaf(p, w, 0.000100950558f);
    p = fmaf(p, w, 0.00134934322f);
    p = fmaf(p, w, -0.00367342844f);
    p = fmaf(p, w, 0.00573950773f);
    p = fmaf(p, w, -0.0076224613f);
    p = fmaf(p, w, 0.00943887047f);
    p = fmaf(p, w, 1.00167406f);
    p = fmaf(p, w, 2.83297682f);
  }
  return p * x;
}

// Fill dst[i] with NOISE_SCALE * normal sample, i = flat row-major index.
// Partitionable threefry: bits = xor of the two outputs, counter = (0, i).
__global__ void noise_fill_k(float* __restrict__ dst, int total,
                             uint32_t kk0, uint32_t kk1) {
  int i = blockIdx.x * blockDim.x + threadIdx.x;
  if (i >= total) return;
  uint32_t o0, o1;
  tf2x32(kk0, kk1, 0u, (uint32_t)i, o0, o1);
  uint32_t bits = o0 ^ o1;
  // uniform in [lo, 1): bitcast((bits>>9)|1.0f) - 1 in [0,1); *(hi-lo) + lo
  float u01 = __uint_as_float((bits >> 9) | 0x3f800000u) - 1.0f;
  const float LO = -0.99999994f;           // nextafter(-1f, 0f)
  float u = fmaxf(LO, fmaf(u01, 2.0f, LO)); // (hi-lo) rounds to exactly 2.0f
  float z = 1.41421356237f * erfinv_xla_f32(u);  // sqrt(2) as f32
  dst[i] = z * 0.1f;
}

// Row L2-normalize: 16 lanes per row, float4 per lane.
__global__ void l2norm_k(const float4* __restrict__ in, float4* __restrict__ out,
                         int nrows) {
  int t = blockIdx.x * blockDim.x + threadIdx.x;
  int r = t >> 4, l = t & 15;
  if (r >= nrows) return;
  float4 v = in[(size_t)r * 16 + l];
  float s = v.x * v.x + v.y * v.y + v.z * v.z + v.w * v.w;
  s += __shfl_xor(s, 1);
  s += __shfl_xor(s, 2);
  s += __shfl_xor(s, 4);
  s += __shfl_xor(s, 8);
  float inv = 1.0f / fmaxf(sqrtf(s), 1e-12f);
  v.x *= inv; v.y *= inv; v.z *= inv; v.w *= inv;
  out[(size_t)r * 16 + l] = v;
}

// Edge scatter: dst[row[e]] += src[col[e]], 16 lanes per edge, float4 each.
__global__ void scatter_k(const int* __restrict__ row, const int* __restrict__ col,
                          const float* __restrict__ src, float* __restrict__ dst,
                          int ne) {
  int t = blockIdx.x * blockDim.x + threadIdx.x;
  int e = t >> 4, l = t & 15;
  if (e >= ne) return;
  int r = row[e], c = col[e];
  float4 v = ((const float4*)(src + (size_t)c * 64))[l];
  float* d = dst + (size_t)r * 64 + (size_t)l * 4;
  atomicAdd(d + 0, v.x);
  atomicAdd(d + 1, v.y);
  atomicAdd(d + 2, v.z);
  atomicAdd(d + 3, v.w);
}

extern "C" void kernel_launch(void* const* d_in, const int* in_sizes, int n_in,
                              void* d_out, int out_size, void* d_ws, size_t ws_size,
                              hipStream_t stream) {
  const float* x = (const float*)d_in[0];
  const int* ei = (const int*)d_in[1];
  float* out = (float*)d_out;

  const int nn = in_sizes[0] / 64;     // 100000
  const int ne = in_sizes[1] / 2;      // 1600000
  const int total = nn * 64;           // 6,400,000
  const int* row = ei;
  const int* col = ei + ne;

  // Per-hop fold_in keys: threefry2x32((0,42), (0,k)) — host precompute.
  uint32_t fk0[3], fk1[3];
  for (int k = 0; k < 3; ++k) tf2x32(0u, 42u, 0u, (uint32_t)k, fk0[k], fk1[k]);

  const int B = 256;
  // out[0] = l2norm(x)
  l2norm_k<<<(nn * 16 + B - 1) / B, B, 0, stream>>>((const float4*)x, (float4*)out, nn);

  for (int k = 0; k < 3; ++k) {
    const float* src = out + (size_t)k * total;
    float* dst = out + (size_t)(k + 1) * total;
    noise_fill_k<<<(total + B - 1) / B, B, 0, stream>>>(dst, total, fk0[k], fk1[k]);
    scatter_k<<<(ne * 16 + B - 1) / B, B, 0, stream>>>(row, col, src, dst, ne);
    l2norm_k<<<(nn * 16 + B - 1) / B, B, 0, stream>>>((const float4*)dst, (float4*)dst, nn);
  }
}

// Round 2
// 654.153 us; speedup vs baseline: 6.3757x; 6.3757x over previous
//
#include <hip/hip_runtime.h>
#include <cstdint>

// ---------------------------------------------------------------------------
// Threefry-2x32, 20 rounds — exact JAX schedule (jax/_src/prng.py)
// ---------------------------------------------------------------------------
static __host__ __device__ inline void tf2x32(uint32_t k0, uint32_t k1,
                                              uint32_t x0, uint32_t x1,
                                              uint32_t &o0, uint32_t &o1) {
  uint32_t ks2 = k0 ^ k1 ^ 0x1BD11BDAu;
  x0 += k0; x1 += k1;
#define TF_R(r) do { x0 += x1; x1 = (x1 << (r)) | (x1 >> (32 - (r))); x1 ^= x0; } while (0)
  TF_R(13); TF_R(15); TF_R(26); TF_R(6);
  x0 += k1; x1 += ks2 + 1u;
  TF_R(17); TF_R(29); TF_R(16); TF_R(24);
  x0 += ks2; x1 += k0 + 2u;
  TF_R(13); TF_R(15); TF_R(26); TF_R(6);
  x0 += k0; x1 += k1 + 3u;
  TF_R(17); TF_R(29); TF_R(16); TF_R(24);
  x0 += k1; x1 += ks2 + 4u;
  TF_R(13); TF_R(15); TF_R(26); TF_R(6);
  x0 += ks2; x1 += k0 + 5u;
#undef TF_R
  o0 = x0; o1 = x1;
}

// XLA's f32 erf_inv expansion (Giles poly, w = -log1p(-x*x)).
__device__ __forceinline__ float erfinv_xla_f32(float x) {
  float w = -log1pf(-x * x);
  float p;
  if (w < 5.0f) {
    w -= 2.5f;
    p = 2.81022636e-08f;
    p = fmaf(p, w, 3.43273939e-07f);
    p = fmaf(p, w, -3.5233877e-06f);
    p = fmaf(p, w, -4.39150654e-06f);
    p = fmaf(p, w, 0.00021858087f);
    p = fmaf(p, w, -0.00125372503f);
    p = fmaf(p, w, -0.00417768164f);
    p = fmaf(p, w, 0.246640727f);
    p = fmaf(p, w, 1.50140941f);
  } else {
    w = sqrtf(w) - 3.0f;
    p = -0.000200214257f;
    p = fmaf(p, w, 0.000100950558f);
    p = fmaf(p, w, 0.00134934322f);
    p = fmaf(p, w, -0.00367342844f);
    p = fmaf(p, w, 0.00573950773f);
    p = fmaf(p, w, -0.0076224613f);
    p = fmaf(p, w, 0.00943887047f);
    p = fmaf(p, w, 1.00167406f);
    p = fmaf(p, w, 2.83297682f);
  }
  return p * x;
}

__device__ __forceinline__ float noise_val(uint32_t kk0, uint32_t kk1, uint32_t idx) {
  uint32_t o0, o1;
  tf2x32(kk0, kk1, 0u, idx, o0, o1);
  uint32_t bits = o0 ^ o1;
  float u01 = __uint_as_float((bits >> 9) | 0x3f800000u) - 1.0f;
  const float LO = -0.99999994f;            // nextafter(-1f, 0f)
  float u = fmaxf(LO, fmaf(u01, 2.0f, LO)); // hi-lo rounds to exactly 2.0f
  return 0.1f * 1.41421356237f * erfinv_xla_f32(u);
}

// ---------------------------------------------------------------------------
// CSR build: counts -> 3-phase exclusive scan -> bucket fill
// ---------------------------------------------------------------------------
__global__ void zero_k(int* p, int n) {
  int i = blockIdx.x * blockDim.x + threadIdx.x;
  if (i < n) p[i] = 0;
}

__global__ void hist_k(const int* __restrict__ row, int* __restrict__ counts, int ne) {
  int e = blockIdx.x * blockDim.x + threadIdx.x;
  if (e < ne) atomicAdd(&counts[row[e]], 1);
}

// Phase A: per-256-block sums
__global__ void blocksum_k(const int* __restrict__ counts, int* __restrict__ bsum, int n) {
  int i = blockIdx.x * 256 + threadIdx.x;
  int v = (i < n) ? counts[i] : 0;
  for (int d = 1; d < 64; d <<= 1) v += __shfl_xor(v, d);
  __shared__ int ws[4];
  if ((threadIdx.x & 63) == 0) ws[threadIdx.x >> 6] = v;
  __syncthreads();
  if (threadIdx.x == 0) bsum[blockIdx.x] = ws[0] + ws[1] + ws[2] + ws[3];
}

// Phase B: single-block exclusive scan of block sums (nb <= 1024), in place
__global__ void scanb_k(int* __restrict__ bsum, int nb) {
  __shared__ int tmp[1024];
  int t = threadIdx.x;
  int v = (t < nb) ? bsum[t] : 0;
  tmp[t] = v;
  __syncthreads();
  for (int d = 1; d < 1024; d <<= 1) {
    int x = (t >= d) ? tmp[t - d] : 0;
    __syncthreads();
    tmp[t] += x;
    __syncthreads();
  }
  if (t < nb) bsum[t] = tmp[t] - v;  // exclusive
}

// Phase C: per-block scan + global offset -> offsets[] and cursor[]
__global__ void offsets_k(const int* __restrict__ counts, const int* __restrict__ bsumExcl,
                          int* __restrict__ offsets, int* __restrict__ cursor, int n) {
  int i = blockIdx.x * 256 + threadIdx.x;
  int v = (i < n) ? counts[i] : 0;
  __shared__ int tmp[256];
  tmp[threadIdx.x] = v;
  __syncthreads();
  for (int d = 1; d < 256; d <<= 1) {
    int x = (threadIdx.x >= d) ? tmp[threadIdx.x - d] : 0;
    __syncthreads();
    tmp[threadIdx.x] += x;
    __syncthreads();
  }
  int excl = tmp[threadIdx.x] - v + bsumExcl[blockIdx.x];
  if (i < n) { offsets[i] = excl; cursor[i] = excl; }
  if (i == n - 1) offsets[n] = excl + v;
}

__global__ void fill_k(const int* __restrict__ row, const int* __restrict__ col,
                       int* __restrict__ cursor, int* __restrict__ ecol, int ne) {
  int e = blockIdx.x * blockDim.x + threadIdx.x;
  if (e < ne) {
    int p = atomicAdd(&cursor[row[e]], 1);
    ecol[p] = col[e];
  }
}

// ---------------------------------------------------------------------------
// Fused per-hop kernel: one wave per dest row; 64 lanes = 64 features.
// acc = sum over incoming edges of src[c][lane]; + threefry noise; L2-norm.
// ---------------------------------------------------------------------------
__global__ void agg_k(const float* __restrict__ src, float* __restrict__ dst,
                      const int* __restrict__ offsets, const int* __restrict__ ecol,
                      int nn, uint32_t kk0, uint32_t kk1) {
  int w = (blockIdx.x * blockDim.x + threadIdx.x) >> 6;  // row = wave id
  int lane = threadIdx.x & 63;
  if (w >= nn) return;
  int beg = offsets[w], end = offsets[w + 1];
  float acc = 0.f;
  for (int e = beg; e < end; ++e) {
    int c = __builtin_amdgcn_readfirstlane(ecol[e]);  // wave-uniform -> SGPR
    acc += src[(size_t)c * 64 + lane];                // 256B coalesced per wave
  }
  float v = acc + noise_val(kk0, kk1, (uint32_t)(w * 64 + lane));
  float s = v * v;
  for (int d = 1; d < 64; d <<= 1) s += __shfl_xor(s, d);
  float inv = 1.0f / fmaxf(sqrtf(s), 1e-12f);
  dst[(size_t)w * 64 + lane] = v * inv;
}

// Row L2-normalize for slice 0: 16 lanes per row, float4 per lane.
__global__ void l2norm_k(const float4* __restrict__ in, float4* __restrict__ out,
                         int nrows) {
  int t = blockIdx.x * blockDim.x + threadIdx.x;
  int r = t >> 4, l = t & 15;
  if (r >= nrows) return;
  float4 v = in[(size_t)r * 16 + l];
  float s = v.x * v.x + v.y * v.y + v.z * v.z + v.w * v.w;
  s += __shfl_xor(s, 1);
  s += __shfl_xor(s, 2);
  s += __shfl_xor(s, 4);
  s += __shfl_xor(s, 8);
  float inv = 1.0f / fmaxf(sqrtf(s), 1e-12f);
  v.x *= inv; v.y *= inv; v.z *= inv; v.w *= inv;
  out[(size_t)r * 16 + l] = v;
}

// ---------------------------------------------------------------------------
// Fallback (atomic scatter) — only used if ws_size is too small for CSR.
// ---------------------------------------------------------------------------
__global__ void noise_fill_k(float* __restrict__ dst, int total,
                             uint32_t kk0, uint32_t kk1) {
  int i = blockIdx.x * blockDim.x + threadIdx.x;
  if (i < total) dst[i] = noise_val(kk0, kk1, (uint32_t)i);
}

__global__ void scatter_k(const int* __restrict__ row, const int* __restrict__ col,
                          const float* __restrict__ src, float* __restrict__ dst,
                          int ne) {
  int t = blockIdx.x * blockDim.x + threadIdx.x;
  int e = t >> 4, l = t & 15;
  if (e >= ne) return;
  int r = row[e], c = col[e];
  float4 v = ((const float4*)(src + (size_t)c * 64))[l];
  float* d = dst + (size_t)r * 64 + (size_t)l * 4;
  atomicAdd(d + 0, v.x);
  atomicAdd(d + 1, v.y);
  atomicAdd(d + 2, v.z);
  atomicAdd(d + 3, v.w);
}

extern "C" void kernel_launch(void* const* d_in, const int* in_sizes, int n_in,
                              void* d_out, int out_size, void* d_ws, size_t ws_size,
                              hipStream_t stream) {
  const float* x = (const float*)d_in[0];
  const int* ei = (const int*)d_in[1];
  float* out = (float*)d_out;

  const int nn = in_sizes[0] / 64;     // 100000
  const int ne = in_sizes[1] / 2;      // 1600000
  const int total = nn * 64;
  const int* row = ei;
  const int* col = ei + ne;

  // Per-hop fold_in keys: threefry2x32((0,42), (0,k)) — host precompute.
  uint32_t fk0[3], fk1[3];
  for (int k = 0; k < 3; ++k) tf2x32(0u, 42u, 0u, (uint32_t)k, fk0[k], fk1[k]);

  const int B = 256;
  const int nb = (nn + 255) / 256;

  // d_ws layout (ints): counts[nn] | offsets[nn+1] | cursor[nn] | bsum[1024] | ecol[ne]
  size_t need = ((size_t)nn * 3 + 1 + 1024 + (size_t)ne) * sizeof(int) + 256;
  bool use_csr = (ws_size >= need) && (nb <= 1024);

  // out[0] = l2norm(x)
  l2norm_k<<<(nn * 16 + B - 1) / B, B, 0, stream>>>((const float4*)x, (float4*)out, nn);

  if (use_csr) {
    int* counts  = (int*)d_ws;
    int* offsets = counts + nn;
    int* cursor  = offsets + nn + 1;
    int* bsum    = cursor + nn;
    int* ecol    = bsum + 1024;

    zero_k<<<(nn + B - 1) / B, B, 0, stream>>>(counts, nn);
    hist_k<<<(ne + B - 1) / B, B, 0, stream>>>(row, counts, ne);
    blocksum_k<<<nb, 256, 0, stream>>>(counts, bsum, nn);
    scanb_k<<<1, 1024, 0, stream>>>(bsum, nb);
    offsets_k<<<nb, 256, 0, stream>>>(counts, bsum, offsets, cursor, nn);
    fill_k<<<(ne + B - 1) / B, B, 0, stream>>>(row, col, cursor, ecol, ne);

    for (int k = 0; k < 3; ++k) {
      const float* src = out + (size_t)k * total;
      float* dst = out + (size_t)(k + 1) * total;
      agg_k<<<(nn * 64 + B - 1) / B, B, 0, stream>>>(src, dst, offsets, ecol,
                                                     nn, fk0[k], fk1[k]);
    }
  } else {
    for (int k = 0; k < 3; ++k) {
      const float* src = out + (size_t)k * total;
      float* dst = out + (size_t)(k + 1) * total;
      noise_fill_k<<<(total + B - 1) / B, B, 0, stream>>>(dst, total, fk0[k], fk1[k]);
      scatter_k<<<(ne * 16 + B - 1) / B, B, 0, stream>>>(row, col, src, dst, ne);
      l2norm_k<<<(nn * 16 + B - 1) / B, B, 0, stream>>>((const float4*)dst, (float4*)dst, nn);
    }
  }
}

// Round 3
// 412.027 us; speedup vs baseline: 10.1223x; 1.5876x over previous
//
#include <hip/hip_runtime.h>
#include <cstdint>

// ---------------------------------------------------------------------------
// Threefry-2x32, 20 rounds — exact JAX schedule (jax/_src/prng.py)
// ---------------------------------------------------------------------------
static __host__ __device__ inline void tf2x32(uint32_t k0, uint32_t k1,
                                              uint32_t x0, uint32_t x1,
                                              uint32_t &o0, uint32_t &o1) {
  uint32_t ks2 = k0 ^ k1 ^ 0x1BD11BDAu;
  x0 += k0; x1 += k1;
#define TF_R(r) do { x0 += x1; x1 = (x1 << (r)) | (x1 >> (32 - (r))); x1 ^= x0; } while (0)
  TF_R(13); TF_R(15); TF_R(26); TF_R(6);
  x0 += k1; x1 += ks2 + 1u;
  TF_R(17); TF_R(29); TF_R(16); TF_R(24);
  x0 += ks2; x1 += k0 + 2u;
  TF_R(13); TF_R(15); TF_R(26); TF_R(6);
  x0 += k0; x1 += k1 + 3u;
  TF_R(17); TF_R(29); TF_R(16); TF_R(24);
  x0 += k1; x1 += ks2 + 4u;
  TF_R(13); TF_R(15); TF_R(26); TF_R(6);
  x0 += ks2; x1 += k0 + 5u;
#undef TF_R
  o0 = x0; o1 = x1;
}

// XLA's f32 erf_inv expansion (Giles poly, w = -log1p(-x*x)).
__device__ __forceinline__ float erfinv_xla_f32(float x) {
  float w = -log1pf(-x * x);
  float p;
  if (w < 5.0f) {
    w -= 2.5f;
    p = 2.81022636e-08f;
    p = fmaf(p, w, 3.43273939e-07f);
    p = fmaf(p, w, -3.5233877e-06f);
    p = fmaf(p, w, -4.39150654e-06f);
    p = fmaf(p, w, 0.00021858087f);
    p = fmaf(p, w, -0.00125372503f);
    p = fmaf(p, w, -0.00417768164f);
    p = fmaf(p, w, 0.246640727f);
    p = fmaf(p, w, 1.50140941f);
  } else {
    w = sqrtf(w) - 3.0f;
    p = -0.000200214257f;
    p = fmaf(p, w, 0.000100950558f);
    p = fmaf(p, w, 0.00134934322f);
    p = fmaf(p, w, -0.00367342844f);
    p = fmaf(p, w, 0.00573950773f);
    p = fmaf(p, w, -0.0076224613f);
    p = fmaf(p, w, 0.00943887047f);
    p = fmaf(p, w, 1.00167406f);
    p = fmaf(p, w, 2.83297682f);
  }
  return p * x;
}

__device__ __forceinline__ float noise_val(uint32_t kk0, uint32_t kk1, uint32_t idx) {
  uint32_t o0, o1;
  tf2x32(kk0, kk1, 0u, idx, o0, o1);
  uint32_t bits = o0 ^ o1;
  float u01 = __uint_as_float((bits >> 9) | 0x3f800000u) - 1.0f;
  const float LO = -0.99999994f;            // nextafter(-1f, 0f)
  float u = fmaxf(LO, fmaf(u01, 2.0f, LO)); // hi-lo rounds to exactly 2.0f
  return 0.1f * 1.41421356237f * erfinv_xla_f32(u);
}

// ---------------------------------------------------------------------------
// CSR build: counts -> 3-phase exclusive scan -> bucket fill
// ---------------------------------------------------------------------------
__global__ void zero_k(int* p, int n) {
  int i = blockIdx.x * blockDim.x + threadIdx.x;
  if (i < n) p[i] = 0;
}

__global__ void hist_k(const int* __restrict__ row, int* __restrict__ counts, int ne) {
  int e = blockIdx.x * blockDim.x + threadIdx.x;
  if (e < ne) atomicAdd(&counts[row[e]], 1);
}

__global__ void blocksum_k(const int* __restrict__ counts, int* __restrict__ bsum, int n) {
  int i = blockIdx.x * 256 + threadIdx.x;
  int v = (i < n) ? counts[i] : 0;
  for (int d = 1; d < 64; d <<= 1) v += __shfl_xor(v, d);
  __shared__ int ws[4];
  if ((threadIdx.x & 63) == 0) ws[threadIdx.x >> 6] = v;
  __syncthreads();
  if (threadIdx.x == 0) bsum[blockIdx.x] = ws[0] + ws[1] + ws[2] + ws[3];
}

__global__ void scanb_k(int* __restrict__ bsum, int nb) {
  __shared__ int tmp[1024];
  int t = threadIdx.x;
  int v = (t < nb) ? bsum[t] : 0;
  tmp[t] = v;
  __syncthreads();
  for (int d = 1; d < 1024; d <<= 1) {
    int x = (t >= d) ? tmp[t - d] : 0;
    __syncthreads();
    tmp[t] += x;
    __syncthreads();
  }
  if (t < nb) bsum[t] = tmp[t] - v;  // exclusive
}

__global__ void offsets_k(const int* __restrict__ counts, const int* __restrict__ bsumExcl,
                          int* __restrict__ offsets, int* __restrict__ cursor, int n) {
  int i = blockIdx.x * 256 + threadIdx.x;
  int v = (i < n) ? counts[i] : 0;
  __shared__ int tmp[256];
  tmp[threadIdx.x] = v;
  __syncthreads();
  for (int d = 1; d < 256; d <<= 1) {
    int x = (threadIdx.x >= d) ? tmp[threadIdx.x - d] : 0;
    __syncthreads();
    tmp[threadIdx.x] += x;
    __syncthreads();
  }
  int excl = tmp[threadIdx.x] - v + bsumExcl[blockIdx.x];
  if (i < n) { offsets[i] = excl; cursor[i] = excl; }
  if (i == n - 1) offsets[n] = excl + v;
}

__global__ void fill_k(const int* __restrict__ row, const int* __restrict__ col,
                       int* __restrict__ cursor, int* __restrict__ ecol, int ne) {
  int e = blockIdx.x * blockDim.x + threadIdx.x;
  if (e < ne) {
    int p = atomicAdd(&cursor[row[e]], 1);
    ecol[p] = col[e];
  }
}

// ---------------------------------------------------------------------------
// Fused per-hop kernel: one wave per dest row; 64 lanes = 64 features.
// Lane-parallel ecol preload + 8-deep gather pipelining to break the
// serial load->add latency chain (the Round-2 bottleneck).
// ---------------------------------------------------------------------------
__global__ void agg_k(const float* __restrict__ src, float* __restrict__ dst,
                      const int* __restrict__ offsets, const int* __restrict__ ecol,
                      int nn, uint32_t kk0, uint32_t kk1) {
  int w = (blockIdx.x * blockDim.x + threadIdx.x) >> 6;  // row = wave id
  int lane = threadIdx.x & 63;
  if (w >= nn) return;
  int beg = offsets[w], end = offsets[w + 1];
  int cnt = end - beg;
  float acc = 0.f;
  for (int base = 0; base < cnt; base += 64) {
    int m = cnt - base; if (m > 64) m = 64;
    // one coalesced 256B load of up to 64 column indices (clamped: always valid)
    int idx = base + lane;
    int myc = ecol[beg + (idx < cnt ? idx : cnt - 1)];
    for (int j = 0; j < m; j += 8) {
      float v[8];
#pragma unroll
      for (int u = 0; u < 8; ++u) {
        int jj = j + u;
        int sl = jj < m ? jj : m - 1;        // uniform clamp -> valid address
        int c = __shfl(myc, sl);
        v[u] = src[(size_t)c * 64 + lane];   // 8 independent gathers in flight
      }
#pragma unroll
      for (int u = 0; u < 8; ++u)
        acc += (j + u < m) ? v[u] : 0.f;     // predicated accumulate
    }
  }
  float nv = acc + noise_val(kk0, kk1, (uint32_t)(w * 64 + lane));
  float s = nv * nv;
  for (int d = 1; d < 64; d <<= 1) s += __shfl_xor(s, d);
  float inv = 1.0f / fmaxf(sqrtf(s), 1e-12f);
  dst[(size_t)w * 64 + lane] = nv * inv;
}

// Row L2-normalize for slice 0: 16 lanes per row, float4 per lane.
__global__ void l2norm_k(const float4* __restrict__ in, float4* __restrict__ out,
                         int nrows) {
  int t = blockIdx.x * blockDim.x + threadIdx.x;
  int r = t >> 4, l = t & 15;
  if (r >= nrows) return;
  float4 v = in[(size_t)r * 16 + l];
  float s = v.x * v.x + v.y * v.y + v.z * v.z + v.w * v.w;
  s += __shfl_xor(s, 1);
  s += __shfl_xor(s, 2);
  s += __shfl_xor(s, 4);
  s += __shfl_xor(s, 8);
  float inv = 1.0f / fmaxf(sqrtf(s), 1e-12f);
  v.x *= inv; v.y *= inv; v.z *= inv; v.w *= inv;
  out[(size_t)r * 16 + l] = v;
}

// ---------------------------------------------------------------------------
// Fallback (atomic scatter) — only used if ws_size is too small for CSR.
// ---------------------------------------------------------------------------
__global__ void noise_fill_k(float* __restrict__ dst, int total,
                             uint32_t kk0, uint32_t kk1) {
  int i = blockIdx.x * blockDim.x + threadIdx.x;
  if (i < total) dst[i] = noise_val(kk0, kk1, (uint32_t)i);
}

__global__ void scatter_k(const int* __restrict__ row, const int* __restrict__ col,
                          const float* __restrict__ src, float* __restrict__ dst,
                          int ne) {
  int t = blockIdx.x * blockDim.x + threadIdx.x;
  int e = t >> 4, l = t & 15;
  if (e >= ne) return;
  int r = row[e], c = col[e];
  float4 v = ((const float4*)(src + (size_t)c * 64))[l];
  float* d = dst + (size_t)r * 64 + (size_t)l * 4;
  atomicAdd(d + 0, v.x);
  atomicAdd(d + 1, v.y);
  atomicAdd(d + 2, v.z);
  atomicAdd(d + 3, v.w);
}

extern "C" void kernel_launch(void* const* d_in, const int* in_sizes, int n_in,
                              void* d_out, int out_size, void* d_ws, size_t ws_size,
                              hipStream_t stream) {
  const float* x = (const float*)d_in[0];
  const int* ei = (const int*)d_in[1];
  float* out = (float*)d_out;

  const int nn = in_sizes[0] / 64;     // 100000
  const int ne = in_sizes[1] / 2;      // 1600000
  const int total = nn * 64;
  const int* row = ei;
  const int* col = ei + ne;

  // Per-hop fold_in keys: threefry2x32((0,42), (0,k)) — host precompute.
  uint32_t fk0[3], fk1[3];
  for (int k = 0; k < 3; ++k) tf2x32(0u, 42u, 0u, (uint32_t)k, fk0[k], fk1[k]);

  const int B = 256;
  const int nb = (nn + 255) / 256;

  // d_ws layout (ints): counts[nn] | offsets[nn+1] | cursor[nn] | bsum[1024] | ecol[ne]
  size_t need = ((size_t)nn * 3 + 1 + 1024 + (size_t)ne) * sizeof(int) + 256;
  bool use_csr = (ws_size >= need) && (nb <= 1024);

  // out[0] = l2norm(x)
  l2norm_k<<<(nn * 16 + B - 1) / B, B, 0, stream>>>((const float4*)x, (float4*)out, nn);

  if (use_csr) {
    int* counts  = (int*)d_ws;
    int* offsets = counts + nn;
    int* cursor  = offsets + nn + 1;
    int* bsum    = cursor + nn;
    int* ecol    = bsum + 1024;

    zero_k<<<(nn + B - 1) / B, B, 0, stream>>>(counts, nn);
    hist_k<<<(ne + B - 1) / B, B, 0, stream>>>(row, counts, ne);
    blocksum_k<<<nb, 256, 0, stream>>>(counts, bsum, nn);
    scanb_k<<<1, 1024, 0, stream>>>(bsum, nb);
    offsets_k<<<nb, 256, 0, stream>>>(counts, bsum, offsets, cursor, nn);
    fill_k<<<(ne + B - 1) / B, B, 0, stream>>>(row, col, cursor, ecol, ne);

    for (int k = 0; k < 3; ++k) {
      const float* src = out + (size_t)k * total;
      float* dst = out + (size_t)(k + 1) * total;
      agg_k<<<(nn * 64 + B - 1) / B, B, 0, stream>>>(src, dst, offsets, ecol,
                                                     nn, fk0[k], fk1[k]);
    }
  } else {
    for (int k = 0; k < 3; ++k) {
      const float* src = out + (size_t)k * total;
      float* dst = out + (size_t)(k + 1) * total;
      noise_fill_k<<<(total + B - 1) / B, B, 0, stream>>>(dst, total, fk0[k], fk1[k]);
      scatter_k<<<(ne * 16 + B - 1) / B, B, 0, stream>>>(row, col, src, dst, ne);
      l2norm_k<<<(nn * 16 + B - 1) / B, B, 0, stream>>>((const float4*)dst, (float4*)dst, nn);
    }
  }
}